// Round 6
// baseline (4665.435 us; speedup 1.0000x reference)
//
#include <hip/hip_runtime.h>

// ---------------------------------------------------------------------------
// SSM evaluator, MFMA version, R6.
// R5 + per-XCD phase-lock barrier each step. R3-R5's 11.7GB FETCH ≈ grid x
// steps x arena: 32 unsynchronized blocks/XCD each cycling a 384KB weight
// arena per step = 12MB instantaneous demand > 4MB L2 -> thrash. A per-XCD
// arrive-and-spin barrier (perf-only: relaxed atomics, bounded spin, no
// correctness dependency) bounds drift to <1 step so weights are fetched
// once per XCD per step (~0.4GB).
// ---------------------------------------------------------------------------

typedef _Float16 f16x8 __attribute__((ext_vector_type(8)));
typedef _Float16 f16x2 __attribute__((ext_vector_type(2)));
typedef float    f32x4 __attribute__((ext_vector_type(4)));
typedef float    f32x2 __attribute__((ext_vector_type(2)));
typedef unsigned short u16;

#define MFMA16(a,b,c) __builtin_amdgcn_mfma_f32_16x16x32_f16((a),(b),(c),0,0,0)

namespace {
constexpr int S = 128;
constexpr long FRAC_OFF = 25165824L;   // S*3*NC*N
constexpr long XLP_OFF  = 33554432L;
constexpr long ZLP_OFF  = 58720256L;
constexpr float HLOG2PI = 0.91893853320467274f;
constexpr float INVLO   = 1.0f / 2048.0f;

// ws arena offsets (u16 elements). Layout per matrix: [col][k], hi then lo.
constexpr int C1HI = 0,      C1LO = 12288;   // [128][96]  = [Wxh;Wzh] stacked
constexpr int GPHI = 24576,  GPLO = 40960;   // [128][128] = [Wg|Wp]
constexpr int WZHI = 57344,  WZLO = 61440;   // [64][64]
constexpr int SCHI = 65536,  SCLO = 69632;   // [64][64]
constexpr int W1B  = 73728;                  // + f*16384 hi, +8192 lo  [128][64]
constexpr int MSB  = 106496;                 // + f*32768 hi, +16384 lo [128][128] = [Wm|Ws]
constexpr int E1HI = 172032, E1LO = 180224;  // [128][64]
constexpr int E2HI = 188416, E2LO = 192512;  // [32][128]
constexpr int XHI  = 196608, XLO  = 458752;  // [S*B*32] input split planes
constexpr long CNT_BYTE = 1572864;           // barrier counters (8 x uint), after arena
}

__device__ __forceinline__ float sigm(float x)      { return 1.0f / (1.0f + __expf(-x)); }
__device__ __forceinline__ float softplusf_(float x){ return fmaxf(x, 0.f) + __logf(1.f + __expf(-fabsf(x))); }
__device__ __forceinline__ float logsigm(float x)   { return fminf(x, 0.f) - __logf(1.f + __expf(-fabsf(x))); }

__device__ __forceinline__ void split2(float v, _Float16& hi, _Float16& lo) {
    hi = (_Float16)v;
    lo = (_Float16)((v - (float)hi) * 2048.0f);
}

// A-fragment read from a swizzled LDS f16 plane.
__device__ __forceinline__ f16x8 rdA(const u16* t, int row, int k, int strideEls, int swm) {
    int byte = ((row * strideEls + k) * 2) ^ ((row & swm) << 4);
    return *(const f16x8*)((const char*)t + byte);
}
// B-fragment: weights [col][k], contiguous k (L2-resident).
__device__ __forceinline__ f16x8 ldB(const u16* wa, int base, int col, int K, int koff) {
    return *(const f16x8*)(wa + base + col * K + koff);
}

// One (row-tile, col-tile) job: NKS k-slices starting at k0, 3-term hi/lo.
template<int NKS>
__device__ __forceinline__ void mmJob(const u16* Ah, const u16* Al, int astride, int aswm,
                                      int arow, int kf, int k0,
                                      const u16* wa, int bHi, int bLo, int col, int K,
                                      float bias, f32x4& H, f32x4& L)
{
    f16x8 ah[NKS], al[NKS], bh[NKS], bl[NKS];
#pragma unroll
    for (int ks = 0; ks < NKS; ++ks) {
        int k = k0 + ks * 32 + kf;
        bh[ks] = ldB(wa, bHi, col, K, k);
        bl[ks] = ldB(wa, bLo, col, K, k);
        ah[ks] = rdA(Ah, arow, k, astride, aswm);
        al[ks] = rdA(Al, arow, k, astride, aswm);
    }
    H = (f32x4){bias, bias, bias, bias};
    L = (f32x4){0.f, 0.f, 0.f, 0.f};
#pragma unroll
    for (int ks = 0; ks < NKS; ++ks) {
        H = MFMA16(ah[ks], bh[ks], H);
        L = MFMA16(ah[ks], bl[ks], L);
        L = MFMA16(al[ks], bh[ks], L);
    }
}

// write C-fragment to swizzled hi/lo act tile (optionally relu)
template<bool RELU>
__device__ __forceinline__ void stAct(f32x4 H, f32x4 L, int rt, int lng, int col,
                                      u16* th, u16* tl, int strideEls, int swm)
{
#pragma unroll
    for (int q = 0; q < 4; ++q) {
        int row = rt * 16 + lng * 4 + q;
        float v = H[q] + L[q] * INVLO;
        if (RELU) v = fmaxf(v, 0.f);
        _Float16 hi, lo; split2(v, hi, lo);
        int byte = ((row * strideEls + col) * 2) ^ ((row & swm) << 4);
        *(_Float16*)((char*)th + byte) = hi;
        *(_Float16*)((char*)tl + byte) = lo;
    }
}
// write C-fragment (combined f32) to swizzled fp32 scratch
__device__ __forceinline__ void stScr(f32x4 H, f32x4 L, int rt, int lng, int col,
                                      float* s, int strideEls)
{
#pragma unroll
    for (int q = 0; q < 4; ++q) {
        int row = rt * 16 + lng * 4 + q;
        int byte = ((row * strideEls + col) * 4) ^ ((row & 7) << 4);
        *(float*)((char*)s + byte) = H[q] + L[q] * INVLO;
    }
}
__device__ __forceinline__ f32x2 rdS2(const float* s, int strideEls, int row, int c) {
    int byte = ((row * strideEls + c) * 4) ^ ((row & 7) << 4);
    return *(const f32x2*)((const char*)s + byte);
}
__device__ __forceinline__ float rdS1(const float* s, int strideEls, int row, int c) {
    int byte = ((row * strideEls + c) * 4) ^ ((row & 7) << 4);
    return *(const float*)((const char*)s + byte);
}
__device__ __forceinline__ void wrS2(float* s, int strideEls, int row, int c, f32x2 v) {
    int byte = ((row * strideEls + c) * 4) ^ ((row & 7) << 4);
    *(f32x2*)((char*)s + byte) = v;
}
__device__ __forceinline__ void wrF16x2(u16* t, int strideEls, int row, int c, f16x2 v) {
    int byte = ((row * strideEls + c) * 2) ^ ((row & 7) << 4);
    *(f16x2*)((char*)t + byte) = v;
}
__device__ __forceinline__ f16x2 rdF16x2(const u16* t, int strideEls, int row, int c) {
    int byte = ((row * strideEls + c) * 2) ^ ((row & 7) << 4);
    return *(const f16x2*)((const char*)t + byte);
}

// --- prep: build masked/stacked/transposed/split weights + split input ------
__global__ void prep_kernel(const float* __restrict__ input,
                            const float* __restrict__ Wxh, const float* __restrict__ Wzh,
                            const float* __restrict__ Wg,  const float* __restrict__ Wp,
                            const float* __restrict__ Wz,  const float* __restrict__ Wsc,
                            const float* __restrict__ W1,  const float* __restrict__ Wm,
                            const float* __restrict__ Ws_, const float* __restrict__ We1,
                            const float* __restrict__ We2, u16* __restrict__ wa)
{
    int idx = blockIdx.x * 256 + threadIdx.x;
    if (idx < 8) {   // zero the phase-lock counters (fresh every launch/replay)
        ((unsigned*)((char*)wa + CNT_BYTE))[idx] = 0u;
    }
    if (idx < 98304) {
        int hio = 0, loo = 0; float v = 0.f;
        int i = idx;
        if (i < 12288) {                       // C1 [128 col][96 k]: k<32 Wxh, else Wzh
            int col = i / 96, k = i % 96;
            v = (k < 32) ? Wxh[k * 128 + col] : Wzh[(k - 32) * 128 + col];
            hio = C1HI + i; loo = C1LO + i;
        } else if (i < 28672) { int j = i - 12288;   // GP [128][128]
            int col = j >> 7, k = j & 127;
            v = (col < 64) ? Wg[k * 64 + col] : Wp[k * 64 + col - 64];
            hio = GPHI + j; loo = GPLO + j;
        } else if (i < 32768) { int j = i - 28672;   // Wz [64][64]
            int col = j >> 6, k = j & 63; v = Wz[k * 64 + col];
            hio = WZHI + j; loo = WZLO + j;
        } else if (i < 36864) { int j = i - 32768;   // Wsc
            int col = j >> 6, k = j & 63; v = Wsc[k * 64 + col];
            hio = SCHI + j; loo = SCLO + j;
        } else if (i < 53248) { int j = i - 36864;   // W1 [2][128 col][64 k], mask1
            int f = j >> 13, jj = j & 8191;
            int col = jj >> 6, k = jj & 63;
            v = W1[(f * 64 + k) * 128 + col] * (((col % 63) >= k) ? 1.f : 0.f);
            hio = W1B + f * 16384 + jj; loo = hio + 8192;
        } else if (i < 86016) { int j = i - 53248;   // MS [2][128 col][128 k], mask2
            int f = j >> 14, jj = j & 16383;
            int col = jj >> 7, k = jj & 127;
            if (col < 64) v = Wm[(f * 128 + k) * 64 + col] * (((k % 63) < col) ? 1.f : 0.f);
            else { int c = col - 64;
                   v = Ws_[(f * 128 + k) * 64 + c]         * (((k % 63) < c)   ? 1.f : 0.f); }
            hio = MSB + f * 32768 + jj; loo = hio + 16384;
        } else if (i < 94208) { int j = i - 86016;   // We1 [128][64]
            int col = j >> 6, k = j & 63; v = We1[k * 128 + col];
            hio = E1HI + j; loo = E1LO + j;
        } else { int j = i - 94208;                  // We2 [32][128]
            int col = j >> 7, k = j & 127; v = We2[k * 32 + col];
            hio = E2HI + j; loo = E2LO + j;
        }
        _Float16 hi, lo; split2(v, hi, lo);
        wa[hio] = __builtin_bit_cast(u16, hi);
        wa[loo] = __builtin_bit_cast(u16, lo);
    } else {
        int j = idx - 98304;
        if (j < 262144) {                            // input split planes
            float v = input[j];
            _Float16 hi, lo; split2(v, hi, lo);
            wa[XHI + j] = __builtin_bit_cast(u16, hi);
            wa[XLO + j] = __builtin_bit_cast(u16, lo);
        }
    }
}

// --- main scan kernel -------------------------------------------------------
__global__ __launch_bounds__(1024, 4)
void ssm_mfma_kernel(const float* __restrict__ eps, const float* __restrict__ u,
                     const float* __restrict__ bh,  const float* __restrict__ bg,
                     const float* __restrict__ bp,  const float* __restrict__ bz,
                     const float* __restrict__ bsc, const float* __restrict__ b1,
                     const float* __restrict__ bm,  const float* __restrict__ bs,
                     const float* __restrict__ be1, const float* __restrict__ be2,
                     const u16* __restrict__ wa, float* __restrict__ out,
                     unsigned* __restrict__ cnt)
{
    __shared__ u16 tXh[32 * 32],  tXl[32 * 32];    // x tile      (K=32,  swm 3)
    __shared__ u16 tZh[32 * 64],  tZl[32 * 64];    // z state     (K=64,  swm 7)
    __shared__ u16 tHh[32 * 128], tHl[32 * 128];   // h/hh/eh     (K=128, swm 7)
    __shared__ u16 tPh[32 * 64],  tPl[32 * 64];    // relu(prop)  (K=64,  swm 7)
    __shared__ float scrB[32 * 128];               // fp32 scratch (stride 128)
    __shared__ float scrA[2][32 * 64];             // split-K partials (stride 64)
    __shared__ float scrL[32 * 64];                // loc (stride 64)
    __shared__ float lpS[32][33];

    const int tid = threadIdx.x;
    const int ln  = tid & 63, w = tid >> 6;        // wave 0..15
    const int lnc = ln & 15, lng = ln >> 4;
    const int rt  = w >> 3;                        // row-tile 0..1
    const int ct  = w & 7;                         // col-tile 0..7 (16-col)
    const int c2  = w & 3, kh2 = (w >> 2) & 1;     // K=64 split-K decode
    const int ce  = w & 1, kh4 = (w >> 1) & 3;     // K=128 4-way split (P_e)
    const int r0  = blockIdx.x * 32, b0 = r0 & 63;
    const int xcd = blockIdx.x & 7;                // per-XCD barrier group
    const int arow = rt * 16 + lnc;
    const int kf   = lng * 8;
    const int crow = tid >> 5, ccol2 = (tid & 31) * 2;   // C-phase mapping
    const int ecol = tid >> 5, erow  = tid & 31;         // C4 mapping

    for (int i = tid; i < 32 * 64; i += 1024) { tZh[i] = 0; tZl[i] = 0; }
    // stage x(t=0)
    if (tid < 512) {
        int rr = tid >> 4, d2 = (tid & 15) * 2;
        int ge = (b0 + rr) * 32 + d2;
        unsigned xh = *(const unsigned*)(wa + XHI + ge);
        unsigned xl = *(const unsigned*)(wa + XLO + ge);
        int byte = (rr * 64 + d2 * 2) ^ ((rr & 3) << 4);
        *(unsigned*)((char*)tXh + byte) = xh;
        *(unsigned*)((char*)tXl + byte) = xl;
    }
    __syncthreads();

    float lp = 0.f;

    for (int t = 0; t < S; ++t) {
        // ---- per-XCD phase-lock (performance-only, bounded spin) ----
        if (tid == 0) {
            unsigned tgt = (unsigned)(t + 1) * 32u;
            __hip_atomic_fetch_add(&cnt[xcd], 1u, __ATOMIC_RELAXED, __HIP_MEMORY_SCOPE_AGENT);
            int spins = 0;
            while (__hip_atomic_load(&cnt[xcd], __ATOMIC_RELAXED, __HIP_MEMORY_SCOPE_AGENT) < tgt
                   && spins < 1024) {
                ++spins;
                __builtin_amdgcn_s_sleep(2);
            }
        }
        __syncthreads();

        // ---- PH1: eps prefetch, P_h (h = relu([x,z]@C1+bh)), zwz split-K
        f32x2 epsv = *(const f32x2*)(eps + ((size_t)t * 8192 + r0 + crow) * 64 + ccol2);
        {
            int col0 = ct * 16 + lnc;
            f16x8 ah[3], al[3], bh8[3], bl8[3];
#pragma unroll
            for (int ks = 0; ks < 3; ++ks) {
                bh8[ks] = ldB(wa, C1HI, col0, 96, ks * 32 + kf);
                bl8[ks] = ldB(wa, C1LO, col0, 96, ks * 32 + kf);
            }
            ah[0] = rdA(tXh, arow, kf, 32, 3);
            al[0] = rdA(tXl, arow, kf, 32, 3);
#pragma unroll
            for (int ks = 1; ks < 3; ++ks) {
                ah[ks] = rdA(tZh, arow, (ks - 1) * 32 + kf, 64, 7);
                al[ks] = rdA(tZl, arow, (ks - 1) * 32 + kf, 64, 7);
            }
            f32x4 H = {bh[col0], bh[col0], bh[col0], bh[col0]};
            f32x4 L = {0.f, 0.f, 0.f, 0.f};
#pragma unroll
            for (int ks = 0; ks < 3; ++ks) {
                H = MFMA16(ah[ks], bh8[ks], H);
                L = MFMA16(ah[ks], bl8[ks], L);
                L = MFMA16(al[ks], bh8[ks], L);
            }
            stAct<true>(H, L, rt, lng, col0, tHh, tHl, 128, 7);
        }
        {   // zwz partial: z @ Wz, split-K
            int colz = c2 * 16 + lnc;
            f32x4 ZH, ZL;
            mmJob<1>(tZh, tZl, 64, 7, arow, kf, kh2 * 32, wa, WZHI, WZLO, colz, 64,
                     (kh2 == 0) ? bz[colz] : 0.f, ZH, ZL);
            stScr(ZH, ZL, rt, lng, colz, scrA[kh2], 64);
        }
        __syncthreads();

        // ---- PH2: GP = h @ [Wg|Wp] ----
        {
            int col0 = ct * 16 + lnc;
            float bias = (col0 < 64) ? bg[col0] : bp[col0 - 64];
            f32x4 H, L;
            mmJob<4>(tHh, tHl, 128, 7, arow, kf, 0, wa, GPHI, GPLO, col0, 128, bias, H, L);
            stScr(H, L, rt, lng, col0, scrB, 128);
        }
        __syncthreads();

        // ---- C1: gate/loc/relu(prop) ----
        {
            f32x2 gp  = rdS2(scrB, 128, crow, ccol2);
            f32x2 pr  = rdS2(scrB, 128, crow, ccol2 + 64);
            f32x2 zw0 = rdS2(scrA[0], 64, crow, ccol2);
            f32x2 zw1 = rdS2(scrA[1], 64, crow, ccol2);
            f32x2 loc; f16x2 ph_, pl_;
#pragma unroll
            for (int i = 0; i < 2; ++i) {
                float g = sigm(gp[i]);
                loc[i] = (1.f - g) * (zw0[i] + zw1[i]) + g * pr[i];
                float rp = fmaxf(pr[i], 0.f);
                _Float16 hi, lo; split2(rp, hi, lo); ph_[i] = hi; pl_[i] = lo;
            }
            wrS2(scrL, 64, crow, ccol2, loc);
            wrF16x2(tPh, 64, crow, ccol2, ph_);
            wrF16x2(tPl, 64, crow, ccol2, pl_);
        }
        __syncthreads();

        // ---- PH3: sc_pre = relu(prop) @ Wsc, split-K ----
        {
            int colz = c2 * 16 + lnc;
            f32x4 SH, SL;
            mmJob<1>(tPh, tPl, 64, 7, arow, kf, kh2 * 32, wa, SCHI, SCLO, colz, 64,
                     (kh2 == 0) ? bsc[colz] : 0.f, SH, SL);
            stScr(SH, SL, rt, lng, colz, scrA[kh2], 64);
        }
        __syncthreads();

        // ---- C2: scale, z = loc + scale*eps, base_lp ----
        {
            f32x2 s0  = rdS2(scrA[0], 64, crow, ccol2);
            f32x2 s1  = rdS2(scrA[1], 64, crow, ccol2);
            f32x2 loc = rdS2(scrL, 64, crow, ccol2);
            f16x2 zh_, zl_;
            lp = 0.f;
#pragma unroll
            for (int i = 0; i < 2; ++i) {
                float sc = softplusf_(s0[i] + s1[i]) + 0.001f;
                float zv = loc[i] + sc * epsv[i];
                lp += -0.5f * epsv[i] * epsv[i] - __logf(sc) - HLOG2PI;
                _Float16 hi, lo; split2(zv, hi, lo); zh_[i] = hi; zl_[i] = lo;
            }
            wrF16x2(tZh, 64, crow, ccol2, zh_);
            wrF16x2(tZl, 64, crow, ccol2, zl_);
        }
        __syncthreads();

        // ---- IAF flows ----
        for (int f = 0; f < 2; ++f) {
            {   // hh = relu(z @ W1m + b1)
                int col0 = ct * 16 + lnc;
                f32x4 H, L;
                mmJob<2>(tZh, tZl, 64, 7, arow, kf, 0, wa,
                         W1B + f * 16384, W1B + f * 16384 + 8192, col0, 64,
                         b1[f * 128 + col0], H, L);
                stAct<true>(H, L, rt, lng, col0, tHh, tHl, 128, 7);
            }
            __syncthreads();
            {   // [mu|spre] = hh @ MS
                int col0 = ct * 16 + lnc;
                float bias = (col0 < 64) ? bm[f * 64 + col0] : bs[f * 64 + col0 - 64];
                f32x4 H, L;
                mmJob<4>(tHh, tHl, 128, 7, arow, kf, 0, wa,
                         MSB + f * 32768, MSB + f * 32768 + 16384, col0, 128, bias, H, L);
                stScr(H, L, rt, lng, col0, scrB, 128);
            }
            __syncthreads();
            {   // C3: z = sg*z + (1-sg)*mu ; lp -= log(sg)
                f32x2 mu = rdS2(scrB, 128, crow, ccol2);
                f32x2 sp = rdS2(scrB, 128, crow, ccol2 + 64);
                f16x2 zh_ = rdF16x2(tZh, 64, crow, ccol2);
                f16x2 zl_ = rdF16x2(tZl, 64, crow, ccol2);
                f16x2 nzh, nzl;
#pragma unroll
                for (int i = 0; i < 2; ++i) {
                    float zv = (float)zh_[i] + (float)zl_[i] * INVLO;
                    float sg = sigm(sp[i] + 1.0f);
                    float zn = sg * zv + (1.f - sg) * mu[i];
                    lp -= __logf(sg);
                    _Float16 hi, lo; split2(zn, hi, lo); nzh[i] = hi; nzl[i] = lo;
                }
                wrF16x2(tZh, 64, crow, ccol2, nzh);
                wrF16x2(tZl, 64, crow, ccol2, nzl);
                if (f == 1) lpS[crow][tid & 31] = lp;
            }
            __syncthreads();
        }

        // ---- PH6: eh = relu(z @ We1 + be1); u prefetch ----
        {
            int col0 = ct * 16 + lnc;
            f32x4 H, L;
            mmJob<2>(tZh, tZl, 64, 7, arow, kf, 0, wa, E1HI, E1LO, col0, 64,
                     be1[col0], H, L);
            stAct<true>(H, L, rt, lng, col0, tHh, tHl, 128, 7);
        }
        float uv = 0.f;
        if (ecol < 24) {
            uv = u[((size_t)((t * 3 + (ecol >> 3)) * 8 + (ecol & 7))) * 8192 + r0 + erow];
        }
        __syncthreads();

        // ---- PH7: e = eh @ We2 (4-way split-K partials); stage x(t+1) ----
        {
            int cole = ce * 16 + lnc;
            f32x4 H, L;
            mmJob<1>(tHh, tHl, 128, 7, arow, kf, kh4 * 32, wa, E2HI, E2LO, cole, 128,
                     (kh4 == 0) ? be2[cole] : 0.f, H, L);
            stScr(H, L, rt, lng, kh4 * 32 + cole, scrB, 128);
        }
        if (t + 1 < S && tid < 512) {
            int rr = tid >> 4, d2 = (tid & 15) * 2;
            int ge = ((t + 1) * 64 + b0 + rr) * 32 + d2;
            unsigned xh = *(const unsigned*)(wa + XHI + ge);
            unsigned xl = *(const unsigned*)(wa + XLO + ge);
            int byte = (rr * 64 + d2 * 2) ^ ((rr & 3) << 4);
            *(unsigned*)((char*)tXh + byte) = xh;
            *(unsigned*)((char*)tXl + byte) = xl;
        }
        __syncthreads();

        // ---- C4: combine e, write outputs; zlp ----
        {
            float v = 0.f;
#pragma unroll
            for (int k4 = 0; k4 < 4; ++k4) v += rdS1(scrB, 128, erow, k4 * 32 + ecol);
            if (ecol < 24) {
                long plane = ((long)(t * 3 + (ecol >> 3)) * 8 + (ecol & 7)) * 8192 + r0 + erow;
                float sg = sigm(v);
                bool hit = uv < sg;
                out[plane] = hit ? 1.f : 0.f;
                out[XLP_OFF + plane] = hit ? logsigm(v) : logsigm(-v);
            } else {
                long pf = ((long)t * 8 + (ecol & 7)) * 8192 + r0 + erow;
                out[FRAC_OFF + pf] = sigm(v);
            }
            if (tid < 32) {
                float s = 0.f;
#pragma unroll
                for (int g2 = 0; g2 < 32; ++g2) s += lpS[tid][g2];
                out[ZLP_OFF + (long)t * 8192 + r0 + tid] = s;
            }
        }
        // next loop iteration starts with the phase-lock + __syncthreads
    }
}

extern "C" void kernel_launch(void* const* d_in, const int* in_sizes, int n_in,
                              void* d_out, int out_size, void* d_ws, size_t ws_size,
                              hipStream_t stream)
{
    const float* input = (const float*)d_in[0];
    const float* eps   = (const float*)d_in[1];
    const float* u     = (const float*)d_in[2];
    const float* Wxh   = (const float*)d_in[3];
    const float* Wzh   = (const float*)d_in[4];
    const float* bh    = (const float*)d_in[5];
    const float* Wg    = (const float*)d_in[6];
    const float* bg    = (const float*)d_in[7];
    const float* Wp    = (const float*)d_in[8];
    const float* bp    = (const float*)d_in[9];
    const float* Wz    = (const float*)d_in[10];
    const float* bz    = (const float*)d_in[11];
    const float* Wsc   = (const float*)d_in[12];
    const float* bsc   = (const float*)d_in[13];
    const float* W1    = (const float*)d_in[14];
    const float* b1    = (const float*)d_in[15];
    const float* Wm    = (const float*)d_in[16];
    const float* bm    = (const float*)d_in[17];
    const float* Ws    = (const float*)d_in[18];
    const float* bs    = (const float*)d_in[19];
    const float* We1   = (const float*)d_in[20];
    const float* be1   = (const float*)d_in[21];
    const float* We2   = (const float*)d_in[22];
    const float* be2   = (const float*)d_in[23];

    u16* wa = (u16*)d_ws;   // ~1.5 MB used (arena + barrier counters)
    unsigned* cnt = (unsigned*)((char*)d_ws + CNT_BYTE);

    hipLaunchKernelGGL(prep_kernel, dim3(1408), dim3(256), 0, stream,
                       input, Wxh, Wzh, Wg, Wp, Wz, Wsc, W1, Wm, Ws, We1, We2, wa);

    hipLaunchKernelGGL(ssm_mfma_kernel, dim3(256), dim3(1024), 0, stream,
                       eps, u, bh, bg, bp, bz, bsc, b1, bm, bs, be1, be2,
                       wa, (float*)d_out, cnt);
}

// Round 7
// 2959.743 us; speedup vs baseline: 1.5763x; 1.5763x over previous
//
#include <hip/hip_runtime.h>

// ---------------------------------------------------------------------------
// SSM evaluator, MFMA version, R7: WEIGHTS IN REGISTERS.
// R3-R6 showed each block re-fetches the 384KB weight arena from HBM every
// step (11.8GB FETCH) and no L2 policy fixes it. Fix: each of 8 waves holds
// its 16-col tile of every weight matrix in 48 f16x8 registers (192 VGPR),
// loaded ONCE before the 128-step scan. Dual row-tile per wave: one B-register
// feeds both 16-row A-tiles. Per-step global traffic = streaming only.
// 256 blocks x 512 threads, 32 rows/block. hi/lo f16 split as before.
// ---------------------------------------------------------------------------

typedef _Float16 f16x8 __attribute__((ext_vector_type(8)));
typedef _Float16 f16x4 __attribute__((ext_vector_type(4)));
typedef float    f32x4 __attribute__((ext_vector_type(4)));
typedef unsigned short u16;

#define MFMA16(a,b,c) __builtin_amdgcn_mfma_f32_16x16x32_f16((a),(b),(c),0,0,0)

namespace {
constexpr int S = 128;
constexpr long FRAC_OFF = 25165824L;
constexpr long XLP_OFF  = 33554432L;
constexpr long ZLP_OFF  = 58720256L;
constexpr float HLOG2PI = 0.91893853320467274f;
constexpr float INVLO   = 1.0f / 2048.0f;

// ws arena offsets (u16 elements). [col][k] layout, hi then lo.
constexpr int C1HI = 0,      C1LO = 12288;   // [128][96]
constexpr int GPHI = 24576,  GPLO = 40960;   // [128][128]
constexpr int WZHI = 57344,  WZLO = 61440;   // [64][64]
constexpr int SCHI = 65536,  SCLO = 69632;   // [64][64]
constexpr int W1B  = 73728;                  // +f*16384 hi, +8192 lo [128][64]
constexpr int MSB  = 106496;                 // +f*32768 hi, +16384 lo [128][128]
constexpr int E1HI = 172032, E1LO = 180224;  // [128][64]
constexpr int E2HI = 188416, E2LO = 192512;  // [32][128]
constexpr int XHI  = 196608, XLO  = 458752;  // input split planes
}

__device__ __forceinline__ float sigm(float x)      { return 1.0f / (1.0f + __expf(-x)); }
__device__ __forceinline__ float softplusf_(float x){ return fmaxf(x, 0.f) + __logf(1.f + __expf(-fabsf(x))); }
__device__ __forceinline__ float logsigm(float x)   { return fminf(x, 0.f) - __logf(1.f + __expf(-fabsf(x))); }

__device__ __forceinline__ void split2(float v, _Float16& hi, _Float16& lo) {
    hi = (_Float16)v;
    lo = (_Float16)((v - (float)hi) * 2048.0f);
}

__device__ __forceinline__ f16x8 rdA(const u16* t, int row, int k, int strideEls, int swm) {
    int byte = ((row * strideEls + k) * 2) ^ ((row & swm) << 4);
    return *(const f16x8*)((const char*)t + byte);
}
__device__ __forceinline__ f16x8 ldB(const u16* wa, int base, int col, int K, int koff) {
    return *(const f16x8*)(wa + base + col * K + koff);
}

// dual-row-tile MFMA phase with register-resident B fragments
template<int NKS, int STRIDE, int SWM>
__device__ __forceinline__ void mmDual(const u16* Th, const u16* Tl, int lnc, int kf,
                                       const f16x8 (&wh)[NKS], const f16x8 (&wl)[NKS],
                                       float bias, f32x4& H0, f32x4& L0, f32x4& H1, f32x4& L1)
{
    H0 = (f32x4){bias, bias, bias, bias}; H1 = H0;
    L0 = (f32x4){0.f, 0.f, 0.f, 0.f};     L1 = L0;
#pragma unroll
    for (int ks = 0; ks < NKS; ++ks) {
        int k = ks * 32 + kf;
        f16x8 a0h = rdA(Th, lnc,      k, STRIDE, SWM);
        f16x8 a0l = rdA(Tl, lnc,      k, STRIDE, SWM);
        f16x8 a1h = rdA(Th, 16 + lnc, k, STRIDE, SWM);
        f16x8 a1l = rdA(Tl, 16 + lnc, k, STRIDE, SWM);
        H0 = MFMA16(a0h, wh[ks], H0); L0 = MFMA16(a0h, wl[ks], L0); L0 = MFMA16(a0l, wh[ks], L0);
        H1 = MFMA16(a1h, wh[ks], H1); L1 = MFMA16(a1h, wl[ks], L1); L1 = MFMA16(a1l, wh[ks], L1);
    }
}

template<bool RELU>
__device__ __forceinline__ void stAct(f32x4 H, f32x4 L, int rt, int lng, int col,
                                      u16* th, u16* tl, int strideEls, int swm)
{
#pragma unroll
    for (int q = 0; q < 4; ++q) {
        int row = rt * 16 + lng * 4 + q;
        float v = H[q] + L[q] * INVLO;
        if (RELU) v = fmaxf(v, 0.f);
        _Float16 hi, lo; split2(v, hi, lo);
        int byte = ((row * strideEls + col) * 2) ^ ((row & swm) << 4);
        *(_Float16*)((char*)th + byte) = hi;
        *(_Float16*)((char*)tl + byte) = lo;
    }
}
__device__ __forceinline__ void stScr(f32x4 H, f32x4 L, int rt, int lng, int col,
                                      float* s, int strideEls)
{
#pragma unroll
    for (int q = 0; q < 4; ++q) {
        int row = rt * 16 + lng * 4 + q;
        int byte = ((row * strideEls + col) * 4) ^ ((row & 7) << 4);
        *(float*)((char*)s + byte) = H[q] + L[q] * INVLO;
    }
}
__device__ __forceinline__ f32x4 rdS4(const float* s, int strideEls, int row, int c) {
    int byte = ((row * strideEls + c) * 4) ^ ((row & 7) << 4);
    return *(const f32x4*)((const char*)s + byte);
}
__device__ __forceinline__ float rdS1(const float* s, int strideEls, int row, int c) {
    int byte = ((row * strideEls + c) * 4) ^ ((row & 7) << 4);
    return *(const float*)((const char*)s + byte);
}
__device__ __forceinline__ void wrS4(float* s, int strideEls, int row, int c, f32x4 v) {
    int byte = ((row * strideEls + c) * 4) ^ ((row & 7) << 4);
    *(f32x4*)((char*)s + byte) = v;
}
__device__ __forceinline__ void wrF16x4(u16* t, int strideEls, int row, int c, f16x4 v) {
    int byte = ((row * strideEls + c) * 2) ^ ((row & 7) << 4);
    *(f16x4*)((char*)t + byte) = v;
}
__device__ __forceinline__ f16x4 rdF16x4(const u16* t, int strideEls, int row, int c) {
    int byte = ((row * strideEls + c) * 2) ^ ((row & 7) << 4);
    return *(const f16x4*)((const char*)t + byte);
}

// --- prep: masked/stacked/transposed/split weights + split input ------------
__global__ void prep_kernel(const float* __restrict__ input,
                            const float* __restrict__ Wxh, const float* __restrict__ Wzh,
                            const float* __restrict__ Wg,  const float* __restrict__ Wp,
                            const float* __restrict__ Wz,  const float* __restrict__ Wsc,
                            const float* __restrict__ W1,  const float* __restrict__ Wm,
                            const float* __restrict__ Ws_, const float* __restrict__ We1,
                            const float* __restrict__ We2, u16* __restrict__ wa)
{
    int idx = blockIdx.x * 256 + threadIdx.x;
    if (idx < 98304) {
        int hio = 0, loo = 0; float v = 0.f;
        int i = idx;
        if (i < 12288) {
            int col = i / 96, k = i % 96;
            v = (k < 32) ? Wxh[k * 128 + col] : Wzh[(k - 32) * 128 + col];
            hio = C1HI + i; loo = C1LO + i;
        } else if (i < 28672) { int j = i - 12288;
            int col = j >> 7, k = j & 127;
            v = (col < 64) ? Wg[k * 64 + col] : Wp[k * 64 + col - 64];
            hio = GPHI + j; loo = GPLO + j;
        } else if (i < 32768) { int j = i - 28672;
            int col = j >> 6, k = j & 63; v = Wz[k * 64 + col];
            hio = WZHI + j; loo = WZLO + j;
        } else if (i < 36864) { int j = i - 32768;
            int col = j >> 6, k = j & 63; v = Wsc[k * 64 + col];
            hio = SCHI + j; loo = SCLO + j;
        } else if (i < 53248) { int j = i - 36864;
            int f = j >> 13, jj = j & 8191;
            int col = jj >> 6, k = jj & 63;
            v = W1[(f * 64 + k) * 128 + col] * (((col % 63) >= k) ? 1.f : 0.f);
            hio = W1B + f * 16384 + jj; loo = hio + 8192;
        } else if (i < 86016) { int j = i - 53248;
            int f = j >> 14, jj = j & 16383;
            int col = jj >> 7, k = jj & 127;
            if (col < 64) v = Wm[(f * 128 + k) * 64 + col] * (((k % 63) < col) ? 1.f : 0.f);
            else { int c = col - 64;
                   v = Ws_[(f * 128 + k) * 64 + c]         * (((k % 63) < c)   ? 1.f : 0.f); }
            hio = MSB + f * 32768 + jj; loo = hio + 16384;
        } else if (i < 94208) { int j = i - 86016;
            int col = j >> 6, k = j & 63; v = We1[k * 128 + col];
            hio = E1HI + j; loo = E1LO + j;
        } else { int j = i - 94208;
            int col = j >> 7, k = j & 127; v = We2[k * 32 + col];
            hio = E2HI + j; loo = E2LO + j;
        }
        _Float16 hi, lo; split2(v, hi, lo);
        wa[hio] = __builtin_bit_cast(u16, hi);
        wa[loo] = __builtin_bit_cast(u16, lo);
    } else {
        int j = idx - 98304;
        if (j < 262144) {
            float v = input[j];
            _Float16 hi, lo; split2(v, hi, lo);
            wa[XHI + j] = __builtin_bit_cast(u16, hi);
            wa[XLO + j] = __builtin_bit_cast(u16, lo);
        }
    }
}

// --- main scan kernel -------------------------------------------------------
__global__ __launch_bounds__(512, 2)
void ssm_mfma_kernel(const float* __restrict__ eps, const float* __restrict__ u,
                     const float* __restrict__ bh,  const float* __restrict__ bg,
                     const float* __restrict__ bp,  const float* __restrict__ bz,
                     const float* __restrict__ bsc, const float* __restrict__ b1,
                     const float* __restrict__ bm,  const float* __restrict__ bs,
                     const float* __restrict__ be1, const float* __restrict__ be2,
                     const u16* __restrict__ wa, float* __restrict__ out)
{
    __shared__ u16 tXh[32 * 32],  tXl[32 * 32];    // x tile
    __shared__ u16 tZh[32 * 64],  tZl[32 * 64];    // z state
    __shared__ u16 tHh[32 * 128], tHl[32 * 128];   // h/hh/eh
    __shared__ u16 tPh[32 * 64],  tPl[32 * 64];    // relu(prop)
    __shared__ float scrB[32 * 128];               // fp32 scratch
    __shared__ float scrZ[32 * 64];                // z @ Wz
    __shared__ float scrL[32 * 64];                // loc
    __shared__ float lpS[32][16];

    const int tid = threadIdx.x;
    const int ln  = tid & 63, w = tid >> 6;        // wave 0..7
    const int lnc = ln & 15, lng = ln >> 4;
    const int r0  = blockIdx.x * 32, b0 = r0 & 63;
    const int kf  = lng * 8;
    const int col0  = w * 16 + lnc;                // 128-col matrices
    const int colz  = (w & 3) * 16 + lnc;          // WZ (w<4) / SC (w>=4)
    const int colE2 = (w & 1) * 16 + lnc;          // E2 col
    const int khE2  = w >> 1;                      // E2 k-quarter
    const int crow  = tid >> 4, ccol4 = (tid & 15) * 4;   // C-phase map
    const int erow  = tid & 31, c0 = (tid >> 5) * 2;      // C4 map

    // ---- one-time: load this wave's weight tiles into registers ----
    f16x8 wC1h[3], wC1l[3], wGPh[4], wGPl[4], wZSh[2], wZSl[2];
    f16x8 wW1h[2][2], wW1l[2][2], wMSh[2][4], wMSl[2][4];
    f16x8 wE1h[2], wE1l[2], wE2h[1], wE2l[1];
#pragma unroll
    for (int ks = 0; ks < 3; ++ks) {
        wC1h[ks] = ldB(wa, C1HI, col0, 96, ks * 32 + kf);
        wC1l[ks] = ldB(wa, C1LO, col0, 96, ks * 32 + kf);
    }
#pragma unroll
    for (int ks = 0; ks < 4; ++ks) {
        wGPh[ks] = ldB(wa, GPHI, col0, 128, ks * 32 + kf);
        wGPl[ks] = ldB(wa, GPLO, col0, 128, ks * 32 + kf);
    }
    if (w < 4) {
#pragma unroll
        for (int ks = 0; ks < 2; ++ks) {
            wZSh[ks] = ldB(wa, WZHI, colz, 64, ks * 32 + kf);
            wZSl[ks] = ldB(wa, WZLO, colz, 64, ks * 32 + kf);
        }
    } else {
#pragma unroll
        for (int ks = 0; ks < 2; ++ks) {
            wZSh[ks] = ldB(wa, SCHI, colz, 64, ks * 32 + kf);
            wZSl[ks] = ldB(wa, SCLO, colz, 64, ks * 32 + kf);
        }
    }
#pragma unroll
    for (int f = 0; f < 2; ++f) {
#pragma unroll
        for (int ks = 0; ks < 2; ++ks) {
            wW1h[f][ks] = ldB(wa, W1B + f * 16384,        col0, 64, ks * 32 + kf);
            wW1l[f][ks] = ldB(wa, W1B + f * 16384 + 8192, col0, 64, ks * 32 + kf);
        }
#pragma unroll
        for (int ks = 0; ks < 4; ++ks) {
            wMSh[f][ks] = ldB(wa, MSB + f * 32768,         col0, 128, ks * 32 + kf);
            wMSl[f][ks] = ldB(wa, MSB + f * 32768 + 16384, col0, 128, ks * 32 + kf);
        }
    }
#pragma unroll
    for (int ks = 0; ks < 2; ++ks) {
        wE1h[ks] = ldB(wa, E1HI, col0, 64, ks * 32 + kf);
        wE1l[ks] = ldB(wa, E1LO, col0, 64, ks * 32 + kf);
    }
    wE2h[0] = ldB(wa, E2HI, colE2, 128, khE2 * 32 + kf);
    wE2l[0] = ldB(wa, E2LO, colE2, 128, khE2 * 32 + kf);

    // biases (per-lane, constant across steps)
    const float bhv  = bh[col0];
    const float bGPv = (col0 < 64) ? bg[col0] : bp[col0 - 64];
    const float bzsv = (w < 4) ? bz[colz] : bsc[colz];
    float bW1v[2], bMSv[2];
#pragma unroll
    for (int f = 0; f < 2; ++f) {
        bW1v[f] = b1[f * 128 + col0];
        bMSv[f] = (col0 < 64) ? bm[f * 64 + col0] : bs[f * 64 + col0 - 64];
    }
    const float bE1v = be1[col0];
    const float bE2v = (khE2 == 0) ? be2[colE2] : 0.f;

    // init z=0, stage x(t=0)
    for (int i = tid; i < 32 * 64; i += 512) { tZh[i] = 0; tZl[i] = 0; }
    {
        int rr = tid >> 4, d2 = (tid & 15) * 2;
        int ge = (b0 + rr) * 32 + d2;
        unsigned xh = *(const unsigned*)(wa + XHI + ge);
        unsigned xl = *(const unsigned*)(wa + XLO + ge);
        int byte = (rr * 64 + d2 * 2) ^ ((rr & 3) << 4);
        *(unsigned*)((char*)tXh + byte) = xh;
        *(unsigned*)((char*)tXl + byte) = xl;
    }
    __syncthreads();

    for (int t = 0; t < S; ++t) {
        // eps prefetch (used 4 barriers later at C2)
        f32x4 epsv = *(const f32x4*)(eps + ((size_t)t * 8192 + r0 + crow) * 64 + ccol4);

        // ---- PH1: h = relu([x,z]@C1 + bh); waves 0-3: zwz = z@Wz ----
        {
            f32x4 H0 = {bhv, bhv, bhv, bhv}, H1 = H0;
            f32x4 L0 = {0.f, 0.f, 0.f, 0.f}, L1 = L0;
            {
                f16x8 a0h = rdA(tXh, lnc, kf, 32, 3),      a0l = rdA(tXl, lnc, kf, 32, 3);
                f16x8 a1h = rdA(tXh, 16 + lnc, kf, 32, 3), a1l = rdA(tXl, 16 + lnc, kf, 32, 3);
                H0 = MFMA16(a0h, wC1h[0], H0); L0 = MFMA16(a0h, wC1l[0], L0); L0 = MFMA16(a0l, wC1h[0], L0);
                H1 = MFMA16(a1h, wC1h[0], H1); L1 = MFMA16(a1h, wC1l[0], L1); L1 = MFMA16(a1l, wC1h[0], L1);
            }
#pragma unroll
            for (int ks = 1; ks < 3; ++ks) {
                int k = (ks - 1) * 32 + kf;
                f16x8 a0h = rdA(tZh, lnc, k, 64, 7),      a0l = rdA(tZl, lnc, k, 64, 7);
                f16x8 a1h = rdA(tZh, 16 + lnc, k, 64, 7), a1l = rdA(tZl, 16 + lnc, k, 64, 7);
                H0 = MFMA16(a0h, wC1h[ks], H0); L0 = MFMA16(a0h, wC1l[ks], L0); L0 = MFMA16(a0l, wC1h[ks], L0);
                H1 = MFMA16(a1h, wC1h[ks], H1); L1 = MFMA16(a1h, wC1l[ks], L1); L1 = MFMA16(a1l, wC1h[ks], L1);
            }
            stAct<true>(H0, L0, 0, lng, col0, tHh, tHl, 128, 7);
            stAct<true>(H1, L1, 1, lng, col0, tHh, tHl, 128, 7);
        }
        if (w < 4) {
            f32x4 H0, L0, H1, L1;
            mmDual<2, 64, 7>(tZh, tZl, lnc, kf, wZSh, wZSl, bzsv, H0, L0, H1, L1);
            stScr(H0, L0, 0, lng, colz, scrZ, 64);
            stScr(H1, L1, 1, lng, colz, scrZ, 64);
        }
        __syncthreads();

        // ---- PH2: [gate|prop] = h @ GP ----
        {
            f32x4 H0, L0, H1, L1;
            mmDual<4, 128, 7>(tHh, tHl, lnc, kf, wGPh, wGPl, bGPv, H0, L0, H1, L1);
            stScr(H0, L0, 0, lng, col0, scrB, 128);
            stScr(H1, L1, 1, lng, col0, scrB, 128);
        }
        __syncthreads();

        // ---- C1: gate/loc/relu(prop) ----
        {
            f32x4 gp4 = rdS4(scrB, 128, crow, ccol4);
            f32x4 pr4 = rdS4(scrB, 128, crow, 64 + ccol4);
            f32x4 zw4 = rdS4(scrZ, 64, crow, ccol4);
            f32x4 loc4; f16x4 ph4, pl4;
#pragma unroll
            for (int i = 0; i < 4; ++i) {
                float g = sigm(gp4[i]);
                loc4[i] = (1.f - g) * zw4[i] + g * pr4[i];
                float rp = fmaxf(pr4[i], 0.f);
                _Float16 hi, lo; split2(rp, hi, lo); ph4[i] = hi; pl4[i] = lo;
            }
            wrS4(scrL, 64, crow, ccol4, loc4);
            wrF16x4(tPh, 64, crow, ccol4, ph4);
            wrF16x4(tPl, 64, crow, ccol4, pl4);
        }
        __syncthreads();

        // ---- PH3: waves 4-7: spre = relu(prop) @ Wsc ----
        if (w >= 4) {
            f32x4 H0, L0, H1, L1;
            mmDual<2, 64, 7>(tPh, tPl, lnc, kf, wZSh, wZSl, bzsv, H0, L0, H1, L1);
            stScr(H0, L0, 0, lng, colz, scrB, 128);
            stScr(H1, L1, 1, lng, colz, scrB, 128);
        }
        __syncthreads();

        // ---- C2: scale, z = loc + scale*eps, base_lp ----
        float lp = 0.f;
        {
            f32x4 s4   = rdS4(scrB, 128, crow, ccol4);
            f32x4 loc4 = rdS4(scrL, 64, crow, ccol4);
            f16x4 zh4, zl4;
#pragma unroll
            for (int i = 0; i < 4; ++i) {
                float sc = softplusf_(s4[i]) + 0.001f;
                float zv = loc4[i] + sc * epsv[i];
                lp += -0.5f * epsv[i] * epsv[i] - __logf(sc) - HLOG2PI;
                _Float16 hi, lo; split2(zv, hi, lo); zh4[i] = hi; zl4[i] = lo;
            }
            wrF16x4(tZh, 64, crow, ccol4, zh4);
            wrF16x4(tZl, 64, crow, ccol4, zl4);
        }
        __syncthreads();

        // ---- IAF flows ----
#pragma unroll
        for (int f = 0; f < 2; ++f) {
            {   // hh = relu(z @ W1m + b1)
                f32x4 H0, L0, H1, L1;
                mmDual<2, 64, 7>(tZh, tZl, lnc, kf, wW1h[f], wW1l[f], bW1v[f], H0, L0, H1, L1);
                stAct<true>(H0, L0, 0, lng, col0, tHh, tHl, 128, 7);
                stAct<true>(H1, L1, 1, lng, col0, tHh, tHl, 128, 7);
            }
            __syncthreads();
            {   // [mu|spre] = hh @ MS
                f32x4 H0, L0, H1, L1;
                mmDual<4, 128, 7>(tHh, tHl, lnc, kf, wMSh[f], wMSl[f], bMSv[f], H0, L0, H1, L1);
                stScr(H0, L0, 0, lng, col0, scrB, 128);
                stScr(H1, L1, 1, lng, col0, scrB, 128);
            }
            __syncthreads();
            {   // C3: z = sg*z + (1-sg)*mu; lp -= log(sg)
                f32x4 mu4 = rdS4(scrB, 128, crow, ccol4);
                f32x4 sp4 = rdS4(scrB, 128, crow, 64 + ccol4);
                f16x4 zh4 = rdF16x4(tZh, 64, crow, ccol4);
                f16x4 zl4 = rdF16x4(tZl, 64, crow, ccol4);
                f16x4 nzh, nzl;
#pragma unroll
                for (int i = 0; i < 4; ++i) {
                    float zv = (float)zh4[i] + (float)zl4[i] * INVLO;
                    float sg = sigm(sp4[i] + 1.0f);
                    float zn = sg * zv + (1.f - sg) * mu4[i];
                    lp -= __logf(sg);
                    _Float16 hi, lo; split2(zn, hi, lo); nzh[i] = hi; nzl[i] = lo;
                }
                wrF16x4(tZh, 64, crow, ccol4, nzh);
                wrF16x4(tZl, 64, crow, ccol4, nzl);
                if (f == 1) lpS[crow][tid & 15] = lp;
            }
            __syncthreads();
        }

        // ---- PH6: eh = relu(z @ We1 + be1); u prefetch ----
        float uv0 = 0.f, uv1 = 0.f;
        if (c0 < 24) {
            uv0 = u[((size_t)((t * 3 + (c0 >> 3)) * 8 + (c0 & 7))) * 8192 + r0 + erow];
            int c1 = c0 + 1;
            uv1 = u[((size_t)((t * 3 + (c1 >> 3)) * 8 + (c1 & 7))) * 8192 + r0 + erow];
        }
        {
            f32x4 H0, L0, H1, L1;
            mmDual<2, 64, 7>(tZh, tZl, lnc, kf, wE1h, wE1l, bE1v, H0, L0, H1, L1);
            stAct<true>(H0, L0, 0, lng, col0, tHh, tHl, 128, 7);
            stAct<true>(H1, L1, 1, lng, col0, tHh, tHl, 128, 7);
        }
        __syncthreads();

        // ---- PH7: e-partials = eh @ We2 (4-way k-split); stage x(t+1) ----
        {
            f32x4 H0, L0, H1, L1;
            H0 = (f32x4){bE2v, bE2v, bE2v, bE2v}; H1 = H0;
            L0 = (f32x4){0.f, 0.f, 0.f, 0.f};     L1 = L0;
            int k = khE2 * 32 + kf;
            f16x8 a0h = rdA(tHh, lnc, k, 128, 7),      a0l = rdA(tHl, lnc, k, 128, 7);
            f16x8 a1h = rdA(tHh, 16 + lnc, k, 128, 7), a1l = rdA(tHl, 16 + lnc, k, 128, 7);
            H0 = MFMA16(a0h, wE2h[0], H0); L0 = MFMA16(a0h, wE2l[0], L0); L0 = MFMA16(a0l, wE2h[0], L0);
            H1 = MFMA16(a1h, wE2h[0], H1); L1 = MFMA16(a1h, wE2l[0], L1); L1 = MFMA16(a1l, wE2h[0], L1);
            stScr(H0, L0, 0, lng, khE2 * 32 + colE2, scrB, 128);
            stScr(H1, L1, 1, lng, khE2 * 32 + colE2, scrB, 128);
        }
        if (t + 1 < S) {
            int rr = tid >> 4, d2 = (tid & 15) * 2;
            int ge = ((t + 1) * 64 + b0 + rr) * 32 + d2;
            unsigned xh = *(const unsigned*)(wa + XHI + ge);
            unsigned xl = *(const unsigned*)(wa + XLO + ge);
            int byte = (rr * 64 + d2 * 2) ^ ((rr & 3) << 4);
            *(unsigned*)((char*)tXh + byte) = xh;
            *(unsigned*)((char*)tXl + byte) = xl;
        }
        __syncthreads();

        // ---- C4: combine e, write outputs; zlp ----
        {
#pragma unroll
            for (int q = 0; q < 2; ++q) {
                int col = c0 + q;
                float v = 0.f;
#pragma unroll
                for (int kh = 0; kh < 4; ++kh) v += rdS1(scrB, 128, erow, kh * 32 + col);
                if (col < 24) {
                    long plane = ((long)(t * 3 + (col >> 3)) * 8 + (col & 7)) * 8192 + r0 + erow;
                    float sg = sigm(v);
                    bool hit = ((q == 0) ? uv0 : uv1) < sg;
                    out[plane] = hit ? 1.f : 0.f;
                    out[XLP_OFF + plane] = hit ? logsigm(v) : logsigm(-v);
                } else {
                    long pf = ((long)t * 8 + (col & 7)) * 8192 + r0 + erow;
                    out[FRAC_OFF + pf] = sigm(v);
                }
            }
            if (tid < 32) {
                float s = 0.f;
#pragma unroll
                for (int g2 = 0; g2 < 16; ++g2) s += lpS[tid][g2];
                out[ZLP_OFF + (long)t * 8192 + r0 + tid] = s;
            }
        }
        // no barrier: next PH1 writes tH/scrZ only; C4 reads scrB/lpS (disjoint),
        // and PH2's scrB write is behind PH1's barrier.
    }
}

extern "C" void kernel_launch(void* const* d_in, const int* in_sizes, int n_in,
                              void* d_out, int out_size, void* d_ws, size_t ws_size,
                              hipStream_t stream)
{
    const float* input = (const float*)d_in[0];
    const float* eps   = (const float*)d_in[1];
    const float* u     = (const float*)d_in[2];
    const float* Wxh   = (const float*)d_in[3];
    const float* Wzh   = (const float*)d_in[4];
    const float* bh    = (const float*)d_in[5];
    const float* Wg    = (const float*)d_in[6];
    const float* bg    = (const float*)d_in[7];
    const float* Wp    = (const float*)d_in[8];
    const float* bp    = (const float*)d_in[9];
    const float* Wz    = (const float*)d_in[10];
    const float* bz    = (const float*)d_in[11];
    const float* Wsc   = (const float*)d_in[12];
    const float* bsc   = (const float*)d_in[13];
    const float* W1    = (const float*)d_in[14];
    const float* b1    = (const float*)d_in[15];
    const float* Wm    = (const float*)d_in[16];
    const float* bm    = (const float*)d_in[17];
    const float* Ws    = (const float*)d_in[18];
    const float* bs    = (const float*)d_in[19];
    const float* We1   = (const float*)d_in[20];
    const float* be1   = (const float*)d_in[21];
    const float* We2   = (const float*)d_in[22];
    const float* be2   = (const float*)d_in[23];

    u16* wa = (u16*)d_ws;   // ~1.45 MB used

    hipLaunchKernelGGL(prep_kernel, dim3(1408), dim3(256), 0, stream,
                       input, Wxh, Wzh, Wg, Wp, Wz, Wsc, W1, Wm, Ws, We1, We2, wa);

    hipLaunchKernelGGL(ssm_mfma_kernel, dim3(256), dim3(512), 0, stream,
                       eps, u, bh, bg, bp, bz, bsc, b1, bm, bs, be1, be2,
                       wa, (float*)d_out);
}